// Round 5
// baseline (800.559 us; speedup 1.0000x reference)
//
#include <hip/hip_runtime.h>
#include <hip/hip_bf16.h>
#include <stdint.h>

// NSubComplex: 2M-point fused encoder + MLP (105 -> 64 -> sin -> 64 -> sin -> 3) + residual.
// R5 == R4 resubmitted verbatim (R4's bench died in infra: "container failed twice";
// no kernel signal). Theory under test, unchanged:
//   (a) dtype is FP32, proven three ways from R0's artifacts -- WRITE_SIZE 24.0 MB ==
//       2M*3*4B (bf16 would be 12 MB), out_npz 21.35 MB > entire 12 MB raw bf16 output,
//       in_npz 183.7 MB > entire 100 MB raw bf16 inputs. The test label's "bf16" is a
//       hard-coded f-string literal, not a dtype signal. R0's working dispatches were
//       the F32 template instance; R1-R3 NaN'd reading fp32 halves as bf16.
//   (b) single structural change vs R0: single-wave 64-thread workgroups (GRID 12500),
//       phases verbatim from the R0 body. Waves fully independent -- attacks R0's
//       measured ~70% barrier-lockstep idle (VALUBusy 30%, MfmaUtil 6%, occupancy 21%).
//       __syncthreads() in a single-wave block is the compiler's proven lowering.

typedef unsigned short u16t;
typedef __attribute__((ext_vector_type(8))) short short8;   // 8 bf16 = 4 VGPRs (MFMA A/B frag)
typedef __attribute__((ext_vector_type(4))) float f32x4;    // MFMA C/D frag

#define GRID 12500
#define TPW  10   // 12500 blocks * 1 wave * 10 tiles * 16 rows = 2,000,000

__device__ __forceinline__ u16t f2bf(float f) {
    __hip_bfloat16 h = __float2bfloat16(f);
    union { __hip_bfloat16 h; u16t u; } v; v.h = h; return v.u;
}
__device__ __forceinline__ float bf2f(u16t u) {
    union { uint32_t i; float f; } v; v.i = ((uint32_t)u) << 16; return v.f;
}

__global__ __launch_bounds__(64, 4)
void nsub_mlp_kernel(const float* __restrict__ bases,
                     const float* __restrict__ normals,
                     const float* __restrict__ enc,
                     const float* __restrict__ W1, const float* __restrict__ b1,
                     const float* __restrict__ W2, const float* __restrict__ b2,
                     const float* __restrict__ W3, const float* __restrict__ b3,
                     float* __restrict__ out)
{
    // Single-wave block: LDS tiles are block==wave private. Row pads keep ds_read_b128
    // at free 2-way bank aliasing.
    __shared__ u16t Xs [16][136];  // features, K padded 105->128 (zeros), +8 pad
    __shared__ u16t Hs [16][72];   // layer-1 activations, 64 + 8 pad
    __shared__ u16t H2s[16][72];   // layer-2 activations

    const int lane = threadIdx.x;  // 0..63
    const int q    = lane >> 4;    // quad: k-group for A/B frags, row-group for C frag
    const int col  = lane & 15;    // n for B/C frags, m (row) for A frags

    // ---- Preload weight fragments (B-operand layout): elem j of lane <->
    // W[k = kc*32 + q*8 + j][n = nt*16 + col].
    short8 w1f[4][4];
    #pragma unroll
    for (int kc = 0; kc < 4; ++kc)
      #pragma unroll
      for (int nt = 0; nt < 4; ++nt) {
        union { u16t u[8]; short8 v; } t;
        #pragma unroll
        for (int j = 0; j < 8; ++j) {
            const int k = kc*32 + q*8 + j;
            t.u[j] = (k < 105) ? f2bf(W1[k*64 + nt*16 + col]) : (u16t)0;
        }
        w1f[kc][nt] = t.v;
      }
    short8 w2f[2][4];
    #pragma unroll
    for (int kc = 0; kc < 2; ++kc)
      #pragma unroll
      for (int nt = 0; nt < 4; ++nt) {
        union { u16t u[8]; short8 v; } t;
        #pragma unroll
        for (int j = 0; j < 8; ++j) {
            const int k = kc*32 + q*8 + j;
            t.u[j] = f2bf(W2[k*64 + nt*16 + col]);
        }
        w2f[kc][nt] = t.v;
      }
    short8 w3f[2];  // N padded 3 -> 16 with zeros
    #pragma unroll
    for (int kc = 0; kc < 2; ++kc) {
        union { u16t u[8]; short8 v; } t;
        #pragma unroll
        for (int j = 0; j < 8; ++j) {
            const int k = kc*32 + q*8 + j;
            t.u[j] = (col < 3) ? f2bf(W3[k*3 + col]) : (u16t)0;
        }
        w3f[kc] = t.v;
    }
    float bias1[4], bias2[4];
    #pragma unroll
    for (int nt = 0; nt < 4; ++nt) {
        bias1[nt] = b1[nt*16 + col];
        bias2[nt] = b2[nt*16 + col];
    }
    const float bias3 = (col < 3) ? b3[col] : 0.0f;

    for (int t = 0; t < TPW; ++t) {
        const int tile = blockIdx.x + t*GRID;
        const int row0 = tile << 4;

        // ---------- Phase A: feature generation into Xs (bf16) ----------
        {
            const int gr = row0 + col;     // each quad covers all 16 rows
            u16t* xr = &Xs[col][0];
            if (q == 0) {
                #pragma unroll
                for (int j = 0; j < 20; ++j) xr[j] = f2bf(enc[gr*20 + j]);
                xr[20] = f2bf(bases[gr*3+0]);
                xr[21] = f2bf(bases[gr*3+1]);
                xr[22] = f2bf(bases[gr*3+2]);
                xr[71] = f2bf(normals[gr*2+0]);
                xr[72] = f2bf(normals[gr*2+1]);
                #pragma unroll
                for (int j = 105; j < 136; ++j) xr[j] = 0;                // zero K-pad
            } else {
                const int c = q - 1;       // base component 0..2
                float f = bases[gr*3 + c];
                #pragma unroll
                for (int l = 0; l < 8; ++l) {
                    f *= 2.0f;             // 2^(l+1) * base
                    float s, co;
                    __sincosf(f, &s, &co);
                    xr[23 + l*6 + c]     = f2bf(s);
                    xr[23 + l*6 + 3 + c] = f2bf(co);
                }
                if (q == 1) {              // one_blob(normals[:,0]) -> feats 73..88
                    const float n0 = normals[gr*2+0];
                    #pragma unroll
                    for (int k = 0; k < 16; ++k) {
                        const float d = n0 - (float)k*(1.0f/15.0f);
                        xr[73+k] = f2bf(__expf(-50.0f*d*d));   // 1/(2*0.1^2) = 50
                    }
                } else if (q == 3) {       // one_blob(normals[:,1]) -> feats 89..104
                    const float n1 = normals[gr*2+1];
                    #pragma unroll
                    for (int k = 0; k < 16; ++k) {
                        const float d = n1 - (float)k*(1.0f/15.0f);
                        xr[89+k] = f2bf(__expf(-50.0f*d*d));
                    }
                }
            }
        }
        __syncthreads();

        // ---------- Phase B: layer 1 (K=128 padded), sin -> Hs ----------
        {
            f32x4 acc[4];
            #pragma unroll
            for (int nt = 0; nt < 4; ++nt)
                acc[nt] = (f32x4){bias1[nt], bias1[nt], bias1[nt], bias1[nt]};
            #pragma unroll
            for (int kc = 0; kc < 4; ++kc) {
                const short8 a = *(const short8*)(&Xs[col][kc*32 + q*8]); // 16B aligned
                #pragma unroll
                for (int nt = 0; nt < 4; ++nt)
                    acc[nt] = __builtin_amdgcn_mfma_f32_16x16x32_bf16(a, w1f[kc][nt], acc[nt], 0, 0, 0);
            }
            #pragma unroll
            for (int nt = 0; nt < 4; ++nt)
              #pragma unroll
              for (int i = 0; i < 4; ++i)
                  Hs[q*4 + i][nt*16 + col] = f2bf(__sinf(acc[nt][i])); // C-layout: row=q*4+i
        }
        __syncthreads();

        // ---------- Phase C: layer 2 (K=64), sin -> H2s ----------
        {
            f32x4 acc[4];
            #pragma unroll
            for (int nt = 0; nt < 4; ++nt)
                acc[nt] = (f32x4){bias2[nt], bias2[nt], bias2[nt], bias2[nt]};
            #pragma unroll
            for (int kc = 0; kc < 2; ++kc) {
                const short8 a = *(const short8*)(&Hs[col][kc*32 + q*8]);
                #pragma unroll
                for (int nt = 0; nt < 4; ++nt)
                    acc[nt] = __builtin_amdgcn_mfma_f32_16x16x32_bf16(a, w2f[kc][nt], acc[nt], 0, 0, 0);
            }
            #pragma unroll
            for (int nt = 0; nt < 4; ++nt)
              #pragma unroll
              for (int i = 0; i < 4; ++i)
                  H2s[q*4 + i][nt*16 + col] = f2bf(__sinf(acc[nt][i]));
        }
        __syncthreads();

        // ---------- Phase D: layer 3 (K=64, N=3 padded to 16) + residual + store ----------
        {
            f32x4 acc = (f32x4){bias3, bias3, bias3, bias3};
            #pragma unroll
            for (int kc = 0; kc < 2; ++kc) {
                const short8 a = *(const short8*)(&H2s[col][kc*32 + q*8]);
                acc = __builtin_amdgcn_mfma_f32_16x16x32_bf16(a, w3f[kc], acc, 0, 0, 0);
            }
            if (col < 3) {
                #pragma unroll
                for (int i = 0; i < 4; ++i) {
                    const int r2 = row0 + q*4 + i;
                    const float res = bases[r2*3 + col] + acc[i];
                    out[r2*3 + col] = res;
                }
            }
        }
        // No barrier before next Phase A: same-wave DS WAR on Xs/Hs/H2s is in-order
        // (this exact unbarriered hazard existed in the passing R0 kernel).
    }
}

extern "C" void kernel_launch(void* const* d_in, const int* in_sizes, int n_in,
                              void* d_out, int out_size, void* d_ws, size_t ws_size,
                              hipStream_t stream) {
    nsub_mlp_kernel<<<GRID, 64, 0, stream>>>(
        (const float*)d_in[0], (const float*)d_in[1], (const float*)d_in[2],
        (const float*)d_in[3], (const float*)d_in[4],
        (const float*)d_in[5], (const float*)d_in[6],
        (const float*)d_in[7], (const float*)d_in[8],
        (float*)d_out);
}